// Round 1
// baseline (2068.812 us; speedup 1.0000x reference)
//
#include <hip/hip_runtime.h>
#include <math.h>

namespace {
constexpr int Np = 60, P = 60, Nv = 14, S = 5, De = 20, Do = 24, HID = 60;
constexpr int NPP = Np * (Np - 1);   // 3540
constexpr int NPV = Np * Nv;         // 840
}

// ---------------- Kernel A: particle-particle branch ----------------
// One block per batch. Faithful row-major-flatten semantics:
// flat p = rr*120 + c ; f = p/3540 ; e = p%3540 ; i = e/59 ; j' = e%59
// value = x[f%60][ f<60 ? i : (j'<i ? j' : j'+1) ]
struct __align__(16) SmemA {
  float x[P * Np];        // 3600
  float w1[120 * HID];    // 7200, row-major [c][h]
  float w2t[De * HID];    // 1200, transposed [o][h]
  float b1[HID];
  float b2[De];
  float ebar[Np * De];    // [i][o]
};

__global__ __launch_bounds__(256) void pp_kernel(
    const float* __restrict__ x, const float* __restrict__ W1,
    const float* __restrict__ b1, const float* __restrict__ W2,
    const float* __restrict__ b2, float* __restrict__ Ebar)
{
  __shared__ SmemA s;
  const int b = blockIdx.x;
  const int tid = threadIdx.x;
  for (int k = tid; k < P * Np; k += 256) s.x[k] = x[b * P * Np + k];
  for (int k = tid; k < 120 * HID; k += 256) s.w1[k] = W1[k];
  for (int k = tid; k < HID * De; k += 256) {
    int h = k / De, o = k % De;
    s.w2t[o * HID + h] = W2[k];
  }
  if (tid < HID) s.b1[tid] = b1[tid];
  if (tid < De)  s.b2[tid] = b2[tid];
  for (int k = tid; k < Np * De; k += 256) s.ebar[k] = 0.f;
  __syncthreads();

  const int r0 = tid * 14;                  // 14 consecutive rows per thread
  for (int k = 0; k < 14; k += 2) {
    const int rrA = r0 + k;
    if (rrA >= NPP) break;                  // r0 even, k even -> rrB always valid
    const int rrB = rrA + 1;

    float acc0[HID], acc1[HID];
    #pragma unroll
    for (int h4 = 0; h4 < HID / 4; ++h4) {
      float4 bb = reinterpret_cast<const float4*>(s.b1)[h4];
      acc0[4*h4+0] = bb.x; acc0[4*h4+1] = bb.y; acc0[4*h4+2] = bb.z; acc0[4*h4+3] = bb.w;
      acc1[4*h4+0] = bb.x; acc1[4*h4+1] = bb.y; acc1[4*h4+2] = bb.z; acc1[4*h4+3] = bb.w;
    }

    unsigned pA = (unsigned)rrA * 120u;
    unsigned pB = pA + 120u;
    for (int c = 0; c < 120; ++c) {
      unsigned fA = pA / 3540u; unsigned eA = pA - fA * 3540u;
      unsigned iA = eA / 59u;   unsigned jA = eA - iA * 59u;
      unsigned colA = (fA < 60u) ? iA : ((jA < iA) ? jA : jA + 1u);
      unsigned ftA  = (fA < 60u) ? fA : fA - 60u;
      float vA = s.x[ftA * Np + colA];

      unsigned fB = pB / 3540u; unsigned eB = pB - fB * 3540u;
      unsigned iB = eB / 59u;   unsigned jB = eB - iB * 59u;
      unsigned colB = (fB < 60u) ? iB : ((jB < iB) ? jB : jB + 1u);
      unsigned ftB  = (fB < 60u) ? fB : fB - 60u;
      float vB = s.x[ftB * Np + colB];

      const float4* wr = reinterpret_cast<const float4*>(&s.w1[c * HID]);
      #pragma unroll
      for (int h4 = 0; h4 < HID / 4; ++h4) {
        float4 w = wr[h4];
        acc0[4*h4+0] = fmaf(vA, w.x, acc0[4*h4+0]);
        acc0[4*h4+1] = fmaf(vA, w.y, acc0[4*h4+1]);
        acc0[4*h4+2] = fmaf(vA, w.z, acc0[4*h4+2]);
        acc0[4*h4+3] = fmaf(vA, w.w, acc0[4*h4+3]);
        acc1[4*h4+0] = fmaf(vB, w.x, acc1[4*h4+0]);
        acc1[4*h4+1] = fmaf(vB, w.y, acc1[4*h4+1]);
        acc1[4*h4+2] = fmaf(vB, w.z, acc1[4*h4+2]);
        acc1[4*h4+3] = fmaf(vB, w.w, acc1[4*h4+3]);
      }
      ++pA; ++pB;
    }

    #pragma unroll
    for (int h = 0; h < HID; ++h) {
      acc0[h] = fmaxf(acc0[h], 0.f);
      acc1[h] = fmaxf(acc1[h], 0.f);
    }

    const int riA = rrA / 59, riB = rrB / 59;
    for (int o = 0; o < De; ++o) {          // rolled; inner statically unrolled
      const float4* w2r = reinterpret_cast<const float4*>(&s.w2t[o * HID]);
      float sA0 = 0.f, sA1 = 0.f, sA2 = 0.f, sA3 = 0.f;
      float sB0 = 0.f, sB1 = 0.f, sB2 = 0.f, sB3 = 0.f;
      #pragma unroll
      for (int h4 = 0; h4 < HID / 4; ++h4) {
        float4 w = w2r[h4];
        sA0 = fmaf(acc0[4*h4+0], w.x, sA0);
        sA1 = fmaf(acc0[4*h4+1], w.y, sA1);
        sA2 = fmaf(acc0[4*h4+2], w.z, sA2);
        sA3 = fmaf(acc0[4*h4+3], w.w, sA3);
        sB0 = fmaf(acc1[4*h4+0], w.x, sB0);
        sB1 = fmaf(acc1[4*h4+1], w.y, sB1);
        sB2 = fmaf(acc1[4*h4+2], w.z, sB2);
        sB3 = fmaf(acc1[4*h4+3], w.w, sB3);
      }
      float outA = s.b2[o] + ((sA0 + sA1) + (sA2 + sA3));
      float outB = s.b2[o] + ((sB0 + sB1) + (sB2 + sB3));
      atomicAdd(&s.ebar[riA * De + o], outA);
      atomicAdd(&s.ebar[riB * De + o], outB);
    }
  }
  __syncthreads();
  for (int k = tid; k < Np * De; k += 256) Ebar[b * Np * De + k] = s.ebar[k];
}

// ---------------- Kernel B: particle-vertex branch ----------------
// Row t = i*14 + v : input = [ x[b,:,i] (60) , y[b,:,v] (5) ]
struct __align__(16) SmemB {
  float x[P * Np];          // 3600
  float w1[(P + S) * HID];  // 3900
  float w2t[De * HID];      // 1200 transposed
  float b1[HID];
  float b2[De];
  float ebar[Np * De];
  float y[S * Nv];          // 70
};

__global__ __launch_bounds__(256) void pv_kernel(
    const float* __restrict__ x, const float* __restrict__ y,
    const float* __restrict__ W1, const float* __restrict__ b1,
    const float* __restrict__ W2, const float* __restrict__ b2,
    float* __restrict__ Ebar)
{
  __shared__ SmemB s;
  const int b = blockIdx.x;
  const int tid = threadIdx.x;
  for (int k = tid; k < P * Np; k += 256) s.x[k] = x[b * P * Np + k];
  for (int k = tid; k < (P + S) * HID; k += 256) s.w1[k] = W1[k];
  for (int k = tid; k < HID * De; k += 256) {
    int h = k / De, o = k % De;
    s.w2t[o * HID + h] = W2[k];
  }
  if (tid < HID) s.b1[tid] = b1[tid];
  if (tid < De)  s.b2[tid] = b2[tid];
  if (tid < S * Nv) s.y[tid] = y[b * S * Nv + tid];
  for (int k = tid; k < Np * De; k += 256) s.ebar[k] = 0.f;
  __syncthreads();

  const int r0 = tid * 4;
  for (int k = 0; k < 4; k += 2) {
    const int rrA = r0 + k;
    if (rrA >= NPV) break;
    const int rrB = rrA + 1;
    const int iA = rrA / 14, vtA = rrA % 14;
    const int iB = rrB / 14, vtB = rrB % 14;

    float acc0[HID], acc1[HID];
    #pragma unroll
    for (int h4 = 0; h4 < HID / 4; ++h4) {
      float4 bb = reinterpret_cast<const float4*>(s.b1)[h4];
      acc0[4*h4+0] = bb.x; acc0[4*h4+1] = bb.y; acc0[4*h4+2] = bb.z; acc0[4*h4+3] = bb.w;
      acc1[4*h4+0] = bb.x; acc1[4*h4+1] = bb.y; acc1[4*h4+2] = bb.z; acc1[4*h4+3] = bb.w;
    }

    for (int c = 0; c < P; ++c) {
      float vA = s.x[c * Np + iA];
      float vB = s.x[c * Np + iB];
      const float4* wr = reinterpret_cast<const float4*>(&s.w1[c * HID]);
      #pragma unroll
      for (int h4 = 0; h4 < HID / 4; ++h4) {
        float4 w = wr[h4];
        acc0[4*h4+0] = fmaf(vA, w.x, acc0[4*h4+0]);
        acc0[4*h4+1] = fmaf(vA, w.y, acc0[4*h4+1]);
        acc0[4*h4+2] = fmaf(vA, w.z, acc0[4*h4+2]);
        acc0[4*h4+3] = fmaf(vA, w.w, acc0[4*h4+3]);
        acc1[4*h4+0] = fmaf(vB, w.x, acc1[4*h4+0]);
        acc1[4*h4+1] = fmaf(vB, w.y, acc1[4*h4+1]);
        acc1[4*h4+2] = fmaf(vB, w.z, acc1[4*h4+2]);
        acc1[4*h4+3] = fmaf(vB, w.w, acc1[4*h4+3]);
      }
    }
    for (int c = 0; c < S; ++c) {
      float vA = s.y[c * Nv + vtA];
      float vB = s.y[c * Nv + vtB];
      const float4* wr = reinterpret_cast<const float4*>(&s.w1[(P + c) * HID]);
      #pragma unroll
      for (int h4 = 0; h4 < HID / 4; ++h4) {
        float4 w = wr[h4];
        acc0[4*h4+0] = fmaf(vA, w.x, acc0[4*h4+0]);
        acc0[4*h4+1] = fmaf(vA, w.y, acc0[4*h4+1]);
        acc0[4*h4+2] = fmaf(vA, w.z, acc0[4*h4+2]);
        acc0[4*h4+3] = fmaf(vA, w.w, acc0[4*h4+3]);
        acc1[4*h4+0] = fmaf(vB, w.x, acc1[4*h4+0]);
        acc1[4*h4+1] = fmaf(vB, w.y, acc1[4*h4+1]);
        acc1[4*h4+2] = fmaf(vB, w.z, acc1[4*h4+2]);
        acc1[4*h4+3] = fmaf(vB, w.w, acc1[4*h4+3]);
      }
    }

    #pragma unroll
    for (int h = 0; h < HID; ++h) {
      acc0[h] = fmaxf(acc0[h], 0.f);
      acc1[h] = fmaxf(acc1[h], 0.f);
    }

    for (int o = 0; o < De; ++o) {
      const float4* w2r = reinterpret_cast<const float4*>(&s.w2t[o * HID]);
      float sA0 = 0.f, sA1 = 0.f, sA2 = 0.f, sA3 = 0.f;
      float sB0 = 0.f, sB1 = 0.f, sB2 = 0.f, sB3 = 0.f;
      #pragma unroll
      for (int h4 = 0; h4 < HID / 4; ++h4) {
        float4 w = w2r[h4];
        sA0 = fmaf(acc0[4*h4+0], w.x, sA0);
        sA1 = fmaf(acc0[4*h4+1], w.y, sA1);
        sA2 = fmaf(acc0[4*h4+2], w.z, sA2);
        sA3 = fmaf(acc0[4*h4+3], w.w, sA3);
        sB0 = fmaf(acc1[4*h4+0], w.x, sB0);
        sB1 = fmaf(acc1[4*h4+1], w.y, sB1);
        sB2 = fmaf(acc1[4*h4+2], w.z, sB2);
        sB3 = fmaf(acc1[4*h4+3], w.w, sB3);
      }
      float outA = s.b2[o] + ((sA0 + sA1) + (sA2 + sA3));
      float outB = s.b2[o] + ((sB0 + sB1) + (sB2 + sB3));
      atomicAdd(&s.ebar[iA * De + o], outA);
      atomicAdd(&s.ebar[iB * De + o], outB);
    }
  }
  __syncthreads();
  for (int k = tid; k < Np * De; k += 256) Ebar[b * Np * De + k] += s.ebar[k];
}

// ---------------- Kernel C: output MLP + sum + classifier ----------------
struct __align__(16) SmemC {
  float w1[(P + De) * HID];  // 4800
  float w2t[Do * HID];       // 1440 transposed [o][h]
  float b1[HID];
  float b2[Do];
  float wc[Do];
};

__global__ __launch_bounds__(64) void out_kernel(
    const float* __restrict__ x, const float* __restrict__ Ebar,
    const float* __restrict__ W1, const float* __restrict__ b1,
    const float* __restrict__ W2, const float* __restrict__ b2,
    const float* __restrict__ Wc, const float* __restrict__ bc,
    float* __restrict__ out)
{
  __shared__ SmemC s;
  const int b = blockIdx.x;
  const int tid = threadIdx.x;
  for (int k = tid; k < (P + De) * HID; k += 64) s.w1[k] = W1[k];
  for (int k = tid; k < HID * Do; k += 64) {
    int h = k / Do, o = k % Do;
    s.w2t[o * HID + h] = W2[k];
  }
  if (tid < HID) s.b1[tid] = b1[tid];
  if (tid < Do)  s.b2[tid] = b2[tid];
  if (tid < Do)  s.wc[tid] = Wc[tid];
  __syncthreads();

  float out24[Do];
  #pragma unroll
  for (int o = 0; o < Do; ++o) out24[o] = 0.f;

  if (tid < Np) {
    const int i = tid;
    float acc[HID];
    #pragma unroll
    for (int h4 = 0; h4 < HID / 4; ++h4) {
      float4 bb = reinterpret_cast<const float4*>(s.b1)[h4];
      acc[4*h4+0] = bb.x; acc[4*h4+1] = bb.y; acc[4*h4+2] = bb.z; acc[4*h4+3] = bb.w;
    }
    const float* xr = &x[b * P * Np + i * Np];       // J[:, :60] = x row i
    for (int c = 0; c < P; ++c) {
      float v = xr[c];
      const float4* wr = reinterpret_cast<const float4*>(&s.w1[c * HID]);
      #pragma unroll
      for (int h4 = 0; h4 < HID / 4; ++h4) {
        float4 w = wr[h4];
        acc[4*h4+0] = fmaf(v, w.x, acc[4*h4+0]);
        acc[4*h4+1] = fmaf(v, w.y, acc[4*h4+1]);
        acc[4*h4+2] = fmaf(v, w.z, acc[4*h4+2]);
        acc[4*h4+3] = fmaf(v, w.w, acc[4*h4+3]);
      }
    }
    const float* er = &Ebar[b * Np * De + i * De];   // J[:, 60:80]
    for (int c = 0; c < De; ++c) {
      float v = er[c];
      const float4* wr = reinterpret_cast<const float4*>(&s.w1[(P + c) * HID]);
      #pragma unroll
      for (int h4 = 0; h4 < HID / 4; ++h4) {
        float4 w = wr[h4];
        acc[4*h4+0] = fmaf(v, w.x, acc[4*h4+0]);
        acc[4*h4+1] = fmaf(v, w.y, acc[4*h4+1]);
        acc[4*h4+2] = fmaf(v, w.z, acc[4*h4+2]);
        acc[4*h4+3] = fmaf(v, w.w, acc[4*h4+3]);
      }
    }
    #pragma unroll
    for (int h = 0; h < HID; ++h) acc[h] = fmaxf(acc[h], 0.f);

    #pragma unroll
    for (int o = 0; o < Do; ++o) {
      const float4* w2r = reinterpret_cast<const float4*>(&s.w2t[o * HID]);
      float s0 = 0.f, s1 = 0.f, s2 = 0.f, s3 = 0.f;
      #pragma unroll
      for (int h4 = 0; h4 < HID / 4; ++h4) {
        float4 w = w2r[h4];
        s0 = fmaf(acc[4*h4+0], w.x, s0);
        s1 = fmaf(acc[4*h4+1], w.y, s1);
        s2 = fmaf(acc[4*h4+2], w.z, s2);
        s3 = fmaf(acc[4*h4+3], w.w, s3);
      }
      out24[o] = s.b2[o] + ((s0 + s1) + (s2 + s3));
    }
  }

  // sum over the 60 particle rows (lanes 60..63 contribute 0)
  #pragma unroll
  for (int o = 0; o < Do; ++o) {
    float v = out24[o];
    v += __shfl_xor(v, 32);
    v += __shfl_xor(v, 16);
    v += __shfl_xor(v, 8);
    v += __shfl_xor(v, 4);
    v += __shfl_xor(v, 2);
    v += __shfl_xor(v, 1);
    out24[o] = v;
  }
  if (tid == 0) {
    float sdot = bc[0];
    #pragma unroll
    for (int o = 0; o < Do; ++o) sdot = fmaf(out24[o], s.wc[o], sdot);
    out[b] = 1.f / (1.f + expf(-sdot));
  }
}

extern "C" void kernel_launch(void* const* d_in, const int* in_sizes, int n_in,
                              void* d_out, int out_size, void* d_ws, size_t ws_size,
                              hipStream_t stream) {
  const float* x     = (const float*)d_in[0];
  const float* y     = (const float*)d_in[1];
  const float* W1_pp = (const float*)d_in[2];
  const float* b1_pp = (const float*)d_in[3];
  const float* W2_pp = (const float*)d_in[4];
  const float* b2_pp = (const float*)d_in[5];
  const float* W1_pv = (const float*)d_in[6];
  const float* b1_pv = (const float*)d_in[7];
  const float* W2_pv = (const float*)d_in[8];
  const float* b2_pv = (const float*)d_in[9];
  const float* W1_o  = (const float*)d_in[10];
  const float* b1_o  = (const float*)d_in[11];
  const float* W2_o  = (const float*)d_in[12];
  const float* b2_o  = (const float*)d_in[13];
  const float* Wc    = (const float*)d_in[14];
  const float* bc    = (const float*)d_in[15];
  float* out  = (float*)d_out;
  float* Ebar = (float*)d_ws;                 // [B][60][20] f32 = 4.8 MB

  const int Bb = in_sizes[0] / (P * Np);      // 1024

  pp_kernel<<<Bb, 256, 0, stream>>>(x, W1_pp, b1_pp, W2_pp, b2_pp, Ebar);
  pv_kernel<<<Bb, 256, 0, stream>>>(x, y, W1_pv, b1_pv, W2_pv, b2_pv, Ebar);
  out_kernel<<<Bb, 64, 0, stream>>>(x, Ebar, W1_o, b1_o, W2_o, b2_o, Wc, bc, out);
}